// Round 11
// baseline (45.293 us; speedup 1.0000x reference)
//
#include <hip/hip_runtime.h>
#include <hip/hip_bf16.h>

#define MROWS 65536
#define DD 768
#define HH 64

typedef __attribute__((ext_vector_type(8))) short short8;
typedef __attribute__((ext_vector_type(4))) float f32x4;

// f32 -> bf16 round-to-nearest-even (bit trick; NaN irrelevant for this data)
__device__ inline unsigned short f2bf(float x) {
    union { float f; unsigned u; } v; v.f = x;
    unsigned r = v.u + 0x7fffu + ((v.u >> 16) & 1u);
    return (unsigned short)(r >> 16);
}

// identity buckets <=4, floor(log2)+3 above, clamped [0,9] (exact int version)
__device__ inline int bucket(int c) {
    int idx = (c <= 4) ? c : (34 - __clz(c));   // 31 - clz + 3
    idx = idx < 0 ? 0 : idx;
    return idx > 9 ? 9 : idx;
}

// A/B fragment k-map: lane (g = lane>>4, c0 = lane&15), reg j in [0,8):
//   k = (j>>2)*16 + g*4 + (j&3)      (bijective on [0,32))
// NOTE: __builtin_nontemporal_load on the A-stream is ~35% SLOWER regardless
// of k-map (measured rounds 2 and 6) -- never reintroduce it.
//
// ws layout:
//   Wf    : bf16[24][4][64][8]  = 49152 ushort  (98304 B)  -- W_eff in B-fragment order
//   constv: f32[64]             @ 98304          -- b1 + ment @ W1[768:1536]
//   dlut  : f32[10][64]         @ 98560          -- dist_table @ W1[2304:2324]
//   clut  : f32[10][64]         @ 101120         -- counter_table @ W1[2324:2344]
__global__ __launch_bounds__(1024) void precompute_kernel(
                                  const float* __restrict__ ment,
                                  const float* __restrict__ dist_t,
                                  const float* __restrict__ cnt_t,
                                  const float* __restrict__ W1,
                                  const float* __restrict__ b1,
                                  unsigned short* __restrict__ Wf,
                                  float* __restrict__ constv,
                                  float* __restrict__ dlut,
                                  float* __restrict__ clut) {
    __shared__ float red[1024];
    int b = blockIdx.x;
    if (b < 24) {
        int s = b;
        for (int e = threadIdx.x; e < 2048; e += blockDim.x) {
            int t    = e >> 9;          // n-tile 0..3
            int lane = (e >> 3) & 63;
            int j    = e & 7;
            int d = s * 32 + ((j >> 2) << 4) + (((lane >> 4) & 3) << 2) + (j & 3);
            int h = t * 16 + (lane & 15);
            float v = W1[d * HH + h] + ment[d] * W1[(1536 + d) * HH + h];
            Wf[(size_t)((s * 4 + t) * 64 + lane) * 8 + j] = f2bf(v);
        }
    } else if (b == 24) {
        int h = threadIdx.x & 63;
        int chunk = threadIdx.x >> 6;            // 0..15
        float acc = 0.f;
        #pragma unroll 8
        for (int d = chunk * 48; d < chunk * 48 + 48; ++d)
            acc += ment[d] * W1[(768 + d) * HH + h];
        red[threadIdx.x] = acc;
        __syncthreads();
        if (chunk == 0) {
            float s0 = b1[h];
            #pragma unroll
            for (int k = 0; k < 16; ++k) s0 += red[k * 64 + h];
            constv[h] = s0;
        }
    } else if (b == 25) {
        for (int e = threadIdx.x; e < 640; e += blockDim.x) {
            int tt = e >> 6, h = e & 63;
            float a = 0.f;
            #pragma unroll
            for (int k = 0; k < 20; ++k)
                a += dist_t[tt * 20 + k] * W1[(2304 + k) * HH + h];
            dlut[e] = a;
        }
    } else if (b == 26) {
        for (int e = threadIdx.x; e < 640; e += blockDim.x) {
            int tt = e >> 6, h = e & 63;
            float a = 0.f;
            #pragma unroll
            for (int k = 0; k < 20; ++k)
                a += cnt_t[tt * 20 + k] * W1[(2324 + k) * HH + h];
            clut[e] = a;
        }
    }
}

// Round 10 (rerun; round-10 bench was an infra failure -- no device):
// span ladder 256 B -> 512 B. 16 rows/wave (one MFMA row-set),
// slab [16 rows][512 B] = 4 k-steps = 8 KB, double-buffered (16 KB/wave,
// 64 KB/block, 2 blocks/CU -- occupancy unchanged at 8 waves/CU).
// Each A-load instruction: 2 rows x 512-B CONTIGUOUS spans (was 4 x 256 B);
// each DRAM row-visit consumes 512 B (was 256 B). B-traffic per A-byte
// doubles (L2-resident Wf; proven non-load-bearing in round 5).
// Wave-private slabs -> no barriers; compiler tracks all waits.

#define GLOADA(RBUF, S) do {                                            \
    _Pragma("unroll")                                                   \
    for (int t = 0; t < 8; ++t)                                         \
        RBUF[t] = *(const f32x4*)(gA + (size_t)t * 6144 + (size_t)(S) * 512); \
} while (0)

#define GLOADB(BBUF, H) do {                                            \
    _Pragma("unroll")                                                   \
    for (int n = 0; n < 4; ++n) {                                       \
        BBUF[n]     = *(const short8*)(bpl + (size_t)(2 * (H)) * 2048 + n * 512);     \
        BBUF[4 + n] = *(const short8*)(bpl + (size_t)(2 * (H) + 1) * 2048 + n * 512); \
    }                                                                   \
} while (0)

#define DSWRITE(RBUF, S) do {                                           \
    char* wb_ = ldsb + (((S) & 1) << 13);                               \
    _Pragma("unroll")                                                   \
    for (int t = 0; t < 8; ++t) {                                       \
        int row_ = 2 * t + subrow2;                                     \
        *(f32x4*)(wb_ + row_ * 512 + ((piece16) ^ ((row_ & 7) << 4))) = RBUF[t]; \
    }                                                                   \
} while (0)

// COMP2(S, P, BBUF): k-steps 2P, 2P+1 of slab S (4 MFMA each into acc[0..3])
#define COMP2(S, P, BBUF) do {                                          \
    const char* rb_ = ldsb + (((S) & 1) << 13);                         \
    _Pragma("unroll")                                                   \
    for (int s2 = 0; s2 < 2; ++s2) {                                    \
        int sp_ = 2 * (P) + s2;                                         \
        f32x4 a0 = *(const f32x4*)(rb_ + rowb + ((sp_ * 128 + g16) ^ key));      \
        f32x4 a1 = *(const f32x4*)(rb_ + rowb + ((sp_ * 128 + 64 + g16) ^ key)); \
        short8 af;                                                      \
        af[0] = (short)f2bf(a0[0]); af[1] = (short)f2bf(a0[1]);         \
        af[2] = (short)f2bf(a0[2]); af[3] = (short)f2bf(a0[3]);         \
        af[4] = (short)f2bf(a1[0]); af[5] = (short)f2bf(a1[1]);         \
        af[6] = (short)f2bf(a1[2]); af[7] = (short)f2bf(a1[3]);         \
        acc[0] = __builtin_amdgcn_mfma_f32_16x16x32_bf16(af, BBUF[s2 * 4 + 0], acc[0], 0, 0, 0); \
        acc[1] = __builtin_amdgcn_mfma_f32_16x16x32_bf16(af, BBUF[s2 * 4 + 1], acc[1], 0, 0, 0); \
        acc[2] = __builtin_amdgcn_mfma_f32_16x16x32_bf16(af, BBUF[s2 * 4 + 2], acc[2], 0, 0, 0); \
        acc[3] = __builtin_amdgcn_mfma_f32_16x16x32_bf16(af, BBUF[s2 * 4 + 3], acc[3], 0, 0, 0); \
    }                                                                   \
} while (0)

__global__ __launch_bounds__(256, 2) void score_kernel(
    const float* __restrict__ mem,
    const unsigned short* __restrict__ Wf,
    const float* __restrict__ constv,
    const float* __restrict__ dlut,
    const float* __restrict__ clut,
    const float* __restrict__ W2,
    const float* __restrict__ b2p,
    const int* __restrict__ entc,
    const int* __restrict__ lms,
    const int* __restrict__ msp,
    float* __restrict__ out) {

    __shared__ __align__(16) char lds_raw[4][16384];   // 16 KB/wave: 2 x 8-KB slabs

    int wave = threadIdx.x >> 6;
    int lane = threadIdx.x & 63;
    int g  = lane >> 4;     // 0..3
    int c0 = lane & 15;     // 0..15
    int row0 = blockIdx.x * 64 + wave * 16;     // wave's 16 rows

    if (blockIdx.x == 0 && threadIdx.x == 0) out[MROWS] = 0.0f;  // dummy new-cluster score

    char* ldsb = &lds_raw[wave][0];

    // --- staging roles: inst t covers rows {2t, 2t+1}; lane -> row 2t+(lane>>5),
    //     bytes [S*512 + (lane&31)*16, +16)  => 2 x 512-B contiguous spans/inst
    int subrow2 = lane >> 5;            // 0..1
    int piece16 = (lane & 31) * 16;     // byte offset within the 512-B span
    const char* gA = (const char*)mem + (size_t)(row0 + subrow2) * 3072 + (lane & 31) * 16;

    // --- fragment read: row = c0 (512-B LDS stride), XOR key spreads banks
    unsigned key  = (unsigned)((c0 & 7) << 4);
    unsigned rowb = (unsigned)(c0 * 512);
    unsigned g16  = (unsigned)(g * 16);

    const unsigned short* bpl = Wf + lane * 8;

    f32x4 acc[4];
    #pragma unroll
    for (int t = 0; t < 4; ++t) acc[t] = (f32x4){0.f, 0.f, 0.f, 0.f};

    f32x4 rA[8], rB[8];
    short8 bA[8], bB[8];

    // --- software pipeline: 6 slabs x 4 k-steps; A one slab ahead, B one half ahead
    GLOADA(rA, 0); GLOADB(bA, 0);
    DSWRITE(rA, 0);
    GLOADA(rB, 1); GLOADB(bB, 1);

    COMP2(0, 0, bA); GLOADB(bA, 2);  COMP2(0, 1, bB); DSWRITE(rB, 1);
    GLOADA(rA, 2);   GLOADB(bB, 3);
    COMP2(1, 0, bA); GLOADB(bA, 4);  COMP2(1, 1, bB); DSWRITE(rA, 2);
    GLOADA(rB, 3);   GLOADB(bB, 5);
    COMP2(2, 0, bA); GLOADB(bA, 6);  COMP2(2, 1, bB); DSWRITE(rB, 3);
    GLOADA(rA, 4);   GLOADB(bB, 7);
    COMP2(3, 0, bA); GLOADB(bA, 8);  COMP2(3, 1, bB); DSWRITE(rA, 4);
    GLOADA(rB, 5);   GLOADB(bB, 9);
    COMP2(4, 0, bA); GLOADB(bA, 10); COMP2(4, 1, bB); DSWRITE(rB, 5);
    GLOADB(bB, 11);
    COMP2(5, 0, bA);                 COMP2(5, 1, bB);

    // Epilogue. D layout (m89): col = lane&15 (h col), row = g*4 + reg.
    int ms  = msp[0];
    float b2v = b2p[0];
    float cv[4], w2[4];
    #pragma unroll
    for (int t = 0; t < 4; ++t) {
        cv[t] = constv[t * 16 + c0];
        w2[t] = W2[t * 16 + c0];
    }

    #pragma unroll
    for (int i = 0; i < 4; ++i) {
        int row = row0 + g * 4 + i;
        int c    = entc[row];
        int dist = ms - lms[row];
        int db = bucket(dist);
        int cb = bucket(c);
        float part = 0.f;
        #pragma unroll
        for (int t = 0; t < 4; ++t) {
            float a = acc[t][i];
            int hc = t * 16 + c0;
            float h = a + cv[t] + dlut[db * 64 + hc] + clut[cb * 64 + hc];
            h = fmaxf(h, 0.f);
            part += h * w2[t];
        }
        part += __shfl_xor(part, 8, 64);
        part += __shfl_xor(part, 4, 64);
        part += __shfl_xor(part, 2, 64);
        part += __shfl_xor(part, 1, 64);
        if (c0 == 0)
            out[row] = (c > 0) ? (part + b2v) : -10000.0f;
    }
}

extern "C" void kernel_launch(void* const* d_in, const int* in_sizes, int n_in,
                              void* d_out, int out_size, void* d_ws, size_t ws_size,
                              hipStream_t stream) {
    const float* ment   = (const float*)d_in[0];
    const float* mem    = (const float*)d_in[1];
    const float* dist_t = (const float*)d_in[2];
    const float* cnt_t  = (const float*)d_in[3];
    const float* W1     = (const float*)d_in[4];
    const float* b1     = (const float*)d_in[5];
    const float* W2     = (const float*)d_in[6];
    const float* b2     = (const float*)d_in[7];
    const int*   entc   = (const int*)d_in[8];
    const int*   lmsp   = (const int*)d_in[9];
    const int*   msp    = (const int*)d_in[10];

    unsigned short* Wf = (unsigned short*)d_ws;
    float* constv = (float*)((char*)d_ws + 98304);
    float* dlut   = constv + 64;
    float* clut   = dlut + 640;

    precompute_kernel<<<27, 1024, 0, stream>>>(ment, dist_t, cnt_t, W1, b1, Wf, constv, dlut, clut);
    score_kernel<<<1024, 256, 0, stream>>>(mem, Wf, constv, dlut, clut, W2, b2,
                                           entc, lmsp, msp, (float*)d_out);
}

// Round 12
// 42.850 us; speedup vs baseline: 1.0570x; 1.0570x over previous
//
#include <hip/hip_runtime.h>
#include <hip/hip_bf16.h>

#define MROWS 65536
#define DD 768
#define HH 64

typedef __attribute__((ext_vector_type(8))) short short8;
typedef __attribute__((ext_vector_type(4))) float f32x4;

// f32 -> bf16 round-to-nearest-even (bit trick; NaN irrelevant for this data)
__device__ inline unsigned short f2bf(float x) {
    union { float f; unsigned u; } v; v.f = x;
    unsigned r = v.u + 0x7fffu + ((v.u >> 16) & 1u);
    return (unsigned short)(r >> 16);
}

// identity buckets <=4, floor(log2)+3 above, clamped [0,9] (exact int version)
__device__ inline int bucket(int c) {
    int idx = (c <= 4) ? c : (34 - __clz(c));   // 31 - clz + 3
    idx = idx < 0 ? 0 : idx;
    return idx > 9 ? 9 : idx;
}

// A/B fragment k-map: lane (g = lane>>4, c0 = lane&15), reg j in [0,8):
//   k = (j>>2)*16 + g*4 + (j&3)      (bijective on [0,32))
// NOTE: __builtin_nontemporal_load on the A-stream is ~35% SLOWER regardless
// of k-map (measured rounds 2 and 6) -- never reintroduce it.
// NOTE: 512-B spans at 16 rows/wave (round 11) regressed +2.65us: doubled
// L2 B-traffic + halved MFMA amortization beat the wider-span gain. Span
// ladder saturated at 256 B/visit. This file is the round-9 optimum.
//
// ws layout:
//   Wf    : bf16[24][4][64][8]  = 49152 ushort  (98304 B)  -- W_eff in B-fragment order
//   constv: f32[64]             @ 98304          -- b1 + ment @ W1[768:1536]
//   dlut  : f32[10][64]         @ 98560          -- dist_table @ W1[2304:2324]
//   clut  : f32[10][64]         @ 101120         -- counter_table @ W1[2324:2344]
__global__ __launch_bounds__(1024) void precompute_kernel(
                                  const float* __restrict__ ment,
                                  const float* __restrict__ dist_t,
                                  const float* __restrict__ cnt_t,
                                  const float* __restrict__ W1,
                                  const float* __restrict__ b1,
                                  unsigned short* __restrict__ Wf,
                                  float* __restrict__ constv,
                                  float* __restrict__ dlut,
                                  float* __restrict__ clut) {
    __shared__ float red[1024];
    int b = blockIdx.x;
    if (b < 24) {
        int s = b;
        for (int e = threadIdx.x; e < 2048; e += blockDim.x) {
            int t    = e >> 9;          // n-tile 0..3
            int lane = (e >> 3) & 63;
            int j    = e & 7;
            int d = s * 32 + ((j >> 2) << 4) + (((lane >> 4) & 3) << 2) + (j & 3);
            int h = t * 16 + (lane & 15);
            float v = W1[d * HH + h] + ment[d] * W1[(1536 + d) * HH + h];
            Wf[(size_t)((s * 4 + t) * 64 + lane) * 8 + j] = f2bf(v);
        }
    } else if (b == 24) {
        int h = threadIdx.x & 63;
        int chunk = threadIdx.x >> 6;            // 0..15
        float acc = 0.f;
        #pragma unroll 8
        for (int d = chunk * 48; d < chunk * 48 + 48; ++d)
            acc += ment[d] * W1[(768 + d) * HH + h];
        red[threadIdx.x] = acc;
        __syncthreads();
        if (chunk == 0) {
            float s0 = b1[h];
            #pragma unroll
            for (int k = 0; k < 16; ++k) s0 += red[k * 64 + h];
            constv[h] = s0;
        }
    } else if (b == 25) {
        for (int e = threadIdx.x; e < 640; e += blockDim.x) {
            int tt = e >> 6, h = e & 63;
            float a = 0.f;
            #pragma unroll
            for (int k = 0; k < 20; ++k)
                a += dist_t[tt * 20 + k] * W1[(2304 + k) * HH + h];
            dlut[e] = a;
        }
    } else if (b == 26) {
        for (int e = threadIdx.x; e < 640; e += blockDim.x) {
            int tt = e >> 6, h = e & 63;
            float a = 0.f;
            #pragma unroll
            for (int k = 0; k < 20; ++k)
                a += cnt_t[tt * 20 + k] * W1[(2324 + k) * HH + h];
            clut[e] = a;
        }
    }
}

// Round-9 optimum (reverted to after round-11 regression): wave-private LDS
// redistribution -- every A-load instruction covers 4 rows x 256-B contiguous
// spans; regs -> ds_write_b128 into XOR-swizzled [32][256] half-slab (2-slab
// ping-pong, 16 KB/wave); ds_read_b128 fragments. 32 rows/wave.
// No barriers (slab wave-private); compiler tracks all waits.

#define GLOADA(RBUF, H) do {                                            \
    _Pragma("unroll")                                                   \
    for (int t = 0; t < 8; ++t)                                         \
        RBUF[t] = *(const f32x4*)(gA + (size_t)t * 12288 + (size_t)(H) * 256); \
} while (0)

#define GLOADB(BBUF, H) do {                                            \
    _Pragma("unroll")                                                   \
    for (int n = 0; n < 4; ++n) {                                       \
        BBUF[n]     = *(const short8*)(bpl + (size_t)(2 * (H)) * 2048 + n * 512);     \
        BBUF[4 + n] = *(const short8*)(bpl + (size_t)(2 * (H) + 1) * 2048 + n * 512); \
    }                                                                   \
} while (0)

#define DSWRITE(RBUF, H) do {                                           \
    char* wb_ = ldsb + (((H) & 1) << 13);                               \
    _Pragma("unroll")                                                   \
    for (int t = 0; t < 8; ++t)                                         \
        *(f32x4*)(wb_ + t * 1024 + ((t & 1) ? wbase_o : wbase_e)) = RBUF[t]; \
} while (0)

#define COMPH(H, BBUF) do {                                             \
    const char* rb_ = ldsb + (((H) & 1) << 13);                         \
    _Pragma("unroll")                                                   \
    for (int q = 0; q < 2; ++q) {                                       \
        unsigned o0_ = q ? off10 : off00;                               \
        unsigned o1_ = q ? off11 : off01;                               \
        f32x4 a0 = *(const f32x4*)(rb_ + o0_);                          \
        f32x4 a1 = *(const f32x4*)(rb_ + o1_);                          \
        f32x4 d0 = *(const f32x4*)(rb_ + o0_ + 4096);                   \
        f32x4 d1 = *(const f32x4*)(rb_ + o1_ + 4096);                   \
        short8 afA, afB;                                                \
        afA[0] = (short)f2bf(a0[0]); afA[1] = (short)f2bf(a0[1]);       \
        afA[2] = (short)f2bf(a0[2]); afA[3] = (short)f2bf(a0[3]);       \
        afA[4] = (short)f2bf(a1[0]); afA[5] = (short)f2bf(a1[1]);       \
        afA[6] = (short)f2bf(a1[2]); afA[7] = (short)f2bf(a1[3]);       \
        afB[0] = (short)f2bf(d0[0]); afB[1] = (short)f2bf(d0[1]);       \
        afB[2] = (short)f2bf(d0[2]); afB[3] = (short)f2bf(d0[3]);       \
        afB[4] = (short)f2bf(d1[0]); afB[5] = (short)f2bf(d1[1]);       \
        afB[6] = (short)f2bf(d1[2]); afB[7] = (short)f2bf(d1[3]);       \
        acc[0][0] = __builtin_amdgcn_mfma_f32_16x16x32_bf16(afA, BBUF[q * 4 + 0], acc[0][0], 0, 0, 0); \
        acc[0][1] = __builtin_amdgcn_mfma_f32_16x16x32_bf16(afA, BBUF[q * 4 + 1], acc[0][1], 0, 0, 0); \
        acc[0][2] = __builtin_amdgcn_mfma_f32_16x16x32_bf16(afA, BBUF[q * 4 + 2], acc[0][2], 0, 0, 0); \
        acc[0][3] = __builtin_amdgcn_mfma_f32_16x16x32_bf16(afA, BBUF[q * 4 + 3], acc[0][3], 0, 0, 0); \
        acc[1][0] = __builtin_amdgcn_mfma_f32_16x16x32_bf16(afB, BBUF[q * 4 + 0], acc[1][0], 0, 0, 0); \
        acc[1][1] = __builtin_amdgcn_mfma_f32_16x16x32_bf16(afB, BBUF[q * 4 + 1], acc[1][1], 0, 0, 0); \
        acc[1][2] = __builtin_amdgcn_mfma_f32_16x16x32_bf16(afB, BBUF[q * 4 + 2], acc[1][2], 0, 0, 0); \
        acc[1][3] = __builtin_amdgcn_mfma_f32_16x16x32_bf16(afB, BBUF[q * 4 + 3], acc[1][3], 0, 0, 0); \
    }                                                                   \
} while (0)

__global__ __launch_bounds__(256, 2) void score_kernel(
    const float* __restrict__ mem,
    const unsigned short* __restrict__ Wf,
    const float* __restrict__ constv,
    const float* __restrict__ dlut,
    const float* __restrict__ clut,
    const float* __restrict__ W2,
    const float* __restrict__ b2p,
    const int* __restrict__ entc,
    const int* __restrict__ lms,
    const int* __restrict__ msp,
    float* __restrict__ out) {

    __shared__ __align__(16) char lds_raw[4][16384];   // 16 KB per wave (2 x 8 KB halves)

    int wave = threadIdx.x >> 6;
    int lane = threadIdx.x & 63;
    int g  = lane >> 4;     // 0..3
    int c0 = lane & 15;     // 0..15
    int row0 = blockIdx.x * 128 + wave * 32;    // wave's first row (32 rows)

    if (blockIdx.x == 0 && threadIdx.x == 0) out[MROWS] = 0.0f;  // dummy new-cluster score

    char* ldsb = &lds_raw[wave][0];

    // --- staging lane roles: instruction t covers LDS rows 4t..4t+3,
    //     lane i -> row 4t+(i>>4), inner (i&15)*16  (4 x 256-B contiguous spans)
    int subrow = lane >> 4;
    int piece  = lane & 15;
    const char* gA = (const char*)(mem + (size_t)(row0 + subrow) * DD) + piece * 16;
    unsigned wbase_e = (unsigned)(subrow * 256 + ((piece * 16) ^ ((subrow & 7) << 4)));       // t even
    unsigned wbase_o = (unsigned)(subrow * 256 + ((piece * 16) ^ (((4 + subrow) & 7) << 4))); // t odd

    // --- fragment read offsets (row = rs*16 + c0; byte = q*128 + h64*64 + g*16, XOR-swizzled)
    unsigned swzr  = (unsigned)((c0 & 7) << 4);
    unsigned off00 = (unsigned)(c0 * 256 + ((0   + 0  + g * 16) ^ swzr));
    unsigned off01 = (unsigned)(c0 * 256 + ((0   + 64 + g * 16) ^ swzr));
    unsigned off10 = (unsigned)(c0 * 256 + ((128 + 0  + g * 16) ^ swzr));
    unsigned off11 = (unsigned)(c0 * 256 + ((128 + 64 + g * 16) ^ swzr));

    const unsigned short* bpl = Wf + lane * 8;

    f32x4 acc[2][4];
    #pragma unroll
    for (int r = 0; r < 2; ++r)
        #pragma unroll
        for (int t = 0; t < 4; ++t)
            acc[r][t] = (f32x4){0.f, 0.f, 0.f, 0.f};

    f32x4 rA[8], rB[8];
    short8 bA[8], bB[8];

    // --- software pipeline over 12 halves (issue order keeps every consumer
    //     wait from draining a younger prefetch: A two ahead, B one ahead)
    GLOADA(rA, 0);
    GLOADA(rB, 1);
    GLOADB(bA, 0);
    DSWRITE(rA, 0);

    GLOADA(rA, 2);  GLOADB(bB, 1);  DSWRITE(rB, 1);  COMPH(0, bA);
    GLOADA(rB, 3);  GLOADB(bA, 2);  DSWRITE(rA, 2);  COMPH(1, bB);
    GLOADA(rA, 4);  GLOADB(bB, 3);  DSWRITE(rB, 3);  COMPH(2, bA);
    GLOADA(rB, 5);  GLOADB(bA, 4);  DSWRITE(rA, 4);  COMPH(3, bB);
    GLOADA(rA, 6);  GLOADB(bB, 5);  DSWRITE(rB, 5);  COMPH(4, bA);
    GLOADA(rB, 7);  GLOADB(bA, 6);  DSWRITE(rA, 6);  COMPH(5, bB);
    GLOADA(rA, 8);  GLOADB(bB, 7);  DSWRITE(rB, 7);  COMPH(6, bA);
    GLOADA(rB, 9);  GLOADB(bA, 8);  DSWRITE(rA, 8);  COMPH(7, bB);
    GLOADA(rA, 10); GLOADB(bB, 9);  DSWRITE(rB, 9);  COMPH(8, bA);
    GLOADA(rB, 11); GLOADB(bA, 10); DSWRITE(rA, 10); COMPH(9, bB);
                    GLOADB(bB, 11); DSWRITE(rB, 11); COMPH(10, bA);
                                                     COMPH(11, bB);

    // Epilogue. D layout (m89): col = lane&15 (h-tile col), row = g*4 + reg.
    int ms  = msp[0];
    float b2v = b2p[0];
    float cv[4], w2[4];
    #pragma unroll
    for (int t = 0; t < 4; ++t) {
        cv[t] = constv[t * 16 + c0];
        w2[t] = W2[t * 16 + c0];
    }

    #pragma unroll
    for (int r = 0; r < 2; ++r) {
        #pragma unroll
        for (int i = 0; i < 4; ++i) {
            int row = row0 + r * 16 + g * 4 + i;
            int c    = entc[row];
            int dist = ms - lms[row];
            int db = bucket(dist);
            int cb = bucket(c);
            float part = 0.f;
            #pragma unroll
            for (int t = 0; t < 4; ++t) {
                float a = acc[r][t][i];
                int hc = t * 16 + c0;
                float h = a + cv[t] + dlut[db * 64 + hc] + clut[cb * 64 + hc];
                h = fmaxf(h, 0.f);
                part += h * w2[t];
            }
            part += __shfl_xor(part, 8, 64);
            part += __shfl_xor(part, 4, 64);
            part += __shfl_xor(part, 2, 64);
            part += __shfl_xor(part, 1, 64);
            if (c0 == 0)
                out[row] = (c > 0) ? (part + b2v) : -10000.0f;
        }
    }
}

extern "C" void kernel_launch(void* const* d_in, const int* in_sizes, int n_in,
                              void* d_out, int out_size, void* d_ws, size_t ws_size,
                              hipStream_t stream) {
    const float* ment   = (const float*)d_in[0];
    const float* mem    = (const float*)d_in[1];
    const float* dist_t = (const float*)d_in[2];
    const float* cnt_t  = (const float*)d_in[3];
    const float* W1     = (const float*)d_in[4];
    const float* b1     = (const float*)d_in[5];
    const float* W2     = (const float*)d_in[6];
    const float* b2     = (const float*)d_in[7];
    const int*   entc   = (const int*)d_in[8];
    const int*   lmsp   = (const int*)d_in[9];
    const int*   msp    = (const int*)d_in[10];

    unsigned short* Wf = (unsigned short*)d_ws;
    float* constv = (float*)((char*)d_ws + 98304);
    float* dlut   = constv + 64;
    float* clut   = dlut + 640;

    precompute_kernel<<<27, 1024, 0, stream>>>(ment, dist_t, cnt_t, W1, b1, Wf, constv, dlut, clut);
    score_kernel<<<512, 256, 0, stream>>>(mem, Wf, constv, dlut, clut, W2, b2,
                                          entc, lmsp, msp, (float*)d_out);
}